// Round 16
// baseline (639.361 us; speedup 1.0000x reference)
//
#include <hip/hip_runtime.h>

#define HDIM 128
#define NT 32
#define MSZ (HDIM * HDIM)
#define NBLK 512        // blocks for bucket passes
#define MAXNB 1024      // max buckets (Ntot < 1M nodes)
#define BSH 10          // bucket = global_node >> BSH

typedef _Float16 half_t;
typedef __attribute__((ext_vector_type(8))) _Float16 f16x8;
typedef __attribute__((ext_vector_type(4))) float f32x4;

__device__ __forceinline__ f16x8 f16x8_zero() {
  f16x8 v = {0, 0, 0, 0, 0, 0, 0, 0};
  return v;
}

// ---------------- combined edge domain ----------------
// Node domain: [ipip(n_ip) | csrc(n_con) | cdst(n_con) | ipcon(n_con) | conip(n_ip)]

struct BuildArgs {
  const int* src0; const int* dst0;
  const int* src1; const int* dst1;
  const int* src2; const int* dst2;
  const int* src3; const int* dst3;
  const int* src4; const int* dst4;
  int eb1, eb2, eb3, eb4, eb5;
  int no0, no1, no2, no3, no4;
};

__device__ __forceinline__ void resolve(const BuildArgs& a, int gid,
                                        const int*& sp, const int*& dp, int& base, int& no) {
  sp = a.src0; dp = a.dst0; base = 0; no = a.no0;
  if (gid >= a.eb1) { sp = a.src1; dp = a.dst1; base = a.eb1; no = a.no1; }
  if (gid >= a.eb2) { sp = a.src2; dp = a.dst2; base = a.eb2; no = a.no2; }
  if (gid >= a.eb3) { sp = a.src3; dp = a.dst3; base = a.eb3; no = a.no3; }
  if (gid >= a.eb4) { sp = a.src4; dp = a.dst4; base = a.eb4; no = a.no4; }
}

// ---- pass A: per-block bucket histogram ----
__global__ void bucket_count(BuildArgs a, int* __restrict__ counts, int NB, int chunk) {
  __shared__ int h[MAXNB];
  for (int i = threadIdx.x; i < NB; i += 256) h[i] = 0;
  __syncthreads();
  int b = blockIdx.x;
  int lo = b * chunk;
  int hi = lo + chunk; if (hi > a.eb5) hi = a.eb5;
  for (int e = lo + threadIdx.x; e < hi; e += 256) {
    const int *sp, *dp; int base, no;
    resolve(a, e, sp, dp, base, no);
    int g = no + dp[e - base];
    atomicAdd(&h[g >> BSH], 1);
  }
  __syncthreads();
  for (int i = threadIdx.x; i < NB; i += 256) counts[b * NB + i] = h[i];
}

// ---- pass S1: per-bucket exclusive scan over the 512 block counts ----
__global__ void bucket_scan1(const int* __restrict__ counts, int* __restrict__ offs,
                             int* __restrict__ totals, int NB) {
  __shared__ int wsum[4];
  int j = blockIdx.x;
  int t = threadIdx.x;
  int v0 = counts[(2 * t) * NB + j];
  int v1 = counts[(2 * t + 1) * NB + j];
  int s = v0 + v1;
  int lane = t & 63, w = t >> 6;
  int v = s;
  #pragma unroll
  for (int o = 1; o < 64; o <<= 1) {
    int u = __shfl_up(v, o);
    if (lane >= o) v += u;
  }
  if (lane == 63) wsum[w] = v;
  __syncthreads();
  int off = v - s;
  for (int i = 0; i < w; ++i) off += wsum[i];
  offs[(2 * t) * NB + j] = off;
  offs[(2 * t + 1) * NB + j] = off + v0;
  if (t == 255) totals[j] = off + s;
}

// ---- pass S2: exclusive scan over bucket totals -> bases (in place) ----
__global__ void bucket_scan2(int* __restrict__ totals, int NB) {
  __shared__ int buf[MAXNB];
  __shared__ int wsum[4];
  int t = threadIdx.x;
  for (int i = t; i < MAXNB; i += 256) buf[i] = (i < NB) ? totals[i] : 0;
  __syncthreads();
  int e0 = buf[4 * t], e1 = buf[4 * t + 1], e2 = buf[4 * t + 2], e3 = buf[4 * t + 3];
  int s = e0 + e1 + e2 + e3;
  int lane = t & 63, w = t >> 6;
  int v = s;
  #pragma unroll
  for (int o = 1; o < 64; o <<= 1) {
    int u = __shfl_up(v, o);
    if (lane >= o) v += u;
  }
  if (lane == 63) wsum[w] = v;
  __syncthreads();
  int off = v - s;
  for (int i = 0; i < w; ++i) off += wsum[i];
  if (4 * t     < NB) totals[4 * t]     = off;
  if (4 * t + 1 < NB) totals[4 * t + 1] = off + e0;
  if (4 * t + 2 < NB) totals[4 * t + 2] = off + e0 + e1;
  if (4 * t + 3 < NB) totals[4 * t + 3] = off + e0 + e1 + e2;
}

// ---- pass B: partition edges into bucket-grouped (dst,src) arrays ----
__global__ void bucket_part(BuildArgs a, const int* __restrict__ offs,
                            const int* __restrict__ bases,
                            int* __restrict__ ebuf_d, int* __restrict__ ebuf_s,
                            int NB, int chunk) {
  __shared__ int cur[MAXNB];
  int b = blockIdx.x;
  for (int i = threadIdx.x; i < NB; i += 256) cur[i] = bases[i] + offs[b * NB + i];
  __syncthreads();
  int lo = b * chunk;
  int hi = lo + chunk; if (hi > a.eb5) hi = a.eb5;
  for (int e = lo + threadIdx.x; e < hi; e += 256) {
    const int *sp, *dp; int base, no;
    resolve(a, e, sp, dp, base, no);
    int g = no + dp[e - base];
    int p = atomicAdd(&cur[g >> BSH], 1);
    ebuf_d[p] = g;
    ebuf_s[p] = sp[e - base];
  }
}

// ---- hist / scatter on bucketed edges (L2-local addresses) ----
__global__ void hist2_kernel(const int* __restrict__ ebuf_d, int* __restrict__ deg, int E) {
  int e = blockIdx.x * 256 + threadIdx.x;
  if (e < E) atomicAdd(&deg[ebuf_d[e]], 1);
}

__global__ void scatter2_kernel(const int* __restrict__ ebuf_d, const int* __restrict__ ebuf_s,
                                int* __restrict__ cursor, int* __restrict__ col, int E) {
  int e = blockIdx.x * 256 + threadIdx.x;
  if (e < E) {
    int p = atomicAdd(&cursor[ebuf_d[e]], 1);
    col[p] = ebuf_s[e];
  }
}

// ---- rowptr scans ----
__global__ void scan_block_sum(const int* __restrict__ deg, int* __restrict__ partials, int n) {
  __shared__ int red[256];
  int t = threadIdx.x;
  int base = blockIdx.x * 4096;
  int s = 0;
  #pragma unroll
  for (int i = 0; i < 16; ++i) {
    int idx = base + t + i * 256;
    if (idx < n) s += deg[idx];
  }
  red[t] = s;
  __syncthreads();
  for (int o = 128; o > 0; o >>= 1) {
    if (t < o) red[t] += red[t + o];
    __syncthreads();
  }
  if (t == 0) partials[blockIdx.x] = red[0];
}

// parallel exclusive scan over <=256 block partials
__global__ void scan_partials_kernel(int* __restrict__ partials, int* __restrict__ rowptr,
                                     int nb, int n) {
  __shared__ int wsum[4];
  int t = threadIdx.x;
  int v0 = (t < nb) ? partials[t] : 0;
  int lane = t & 63, w = t >> 6;
  int v = v0;
  #pragma unroll
  for (int o = 1; o < 64; o <<= 1) {
    int u = __shfl_up(v, o);
    if (lane >= o) v += u;
  }
  if (lane == 63) wsum[w] = v;
  __syncthreads();
  int off = v - v0;
  for (int i = 0; i < w; ++i) off += wsum[i];
  if (t < nb) partials[t] = off;
  if (t == 255) rowptr[n] = off + v0;
}

__global__ void scan_within(int* __restrict__ deg_cursor, const int* __restrict__ partials,
                            int* __restrict__ rowptr, int n) {
  __shared__ int buf[4096];
  __shared__ int wsum[4];
  int t = threadIdx.x;
  int base = blockIdx.x * 4096;
  #pragma unroll
  for (int i = 0; i < 16; ++i) {
    int idx = base + t + i * 256;
    buf[t + i * 256] = (idx < n) ? deg_cursor[idx] : 0;
  }
  __syncthreads();
  int ex[16];
  int s = 0;
  #pragma unroll
  for (int i = 0; i < 16; ++i) { ex[i] = s; s += buf[t * 16 + i]; }
  int lane = t & 63, w = t >> 6;
  int v = s;
  #pragma unroll
  for (int o = 1; o < 64; o <<= 1) {
    int u = __shfl_up(v, o);
    if (lane >= o) v += u;
  }
  if (lane == 63) wsum[w] = v;
  __syncthreads();
  int off = partials[blockIdx.x] + (v - s);
  for (int i = 0; i < w; ++i) off += wsum[i];
  #pragma unroll
  for (int i = 0; i < 16; ++i) {
    int idx = base + t * 16 + i;
    if (idx < n) { int val = off + ex[i]; rowptr[idx] = val; deg_cursor[idx] = val; }
  }
}

// ---------------- fp32 -> f16 input conversion ----------------

__global__ void cvt_f2h_kernel(const float* __restrict__ in, half_t* __restrict__ out, int n8) {
  int i = blockIdx.x * 256 + threadIdx.x;
  if (i >= n8) return;
  const float4* p = (const float4*)(in + (size_t)i * 8);
  float4 a = p[0], b = p[1];
  f16x8 h = { (_Float16)a.x, (_Float16)a.y, (_Float16)a.z, (_Float16)a.w,
              (_Float16)b.x, (_Float16)b.y, (_Float16)b.z, (_Float16)b.w };
  *(f16x8*)(out + (size_t)i * 8) = h;
}

// ---------------- weight pack: fp32 row-major -> f16 MFMA B-fragment order ----

__global__ void pack_all_kernel(const float* __restrict__ Wl_t, const float* __restrict__ Wr_t,
                                const float* __restrict__ Wl_s, const float* __restrict__ Wr_s,
                                half_t* __restrict__ out) {
  int gid = blockIdx.x * 256 + threadIdx.x;
  if (gid >= 20 * 2048) return;
  int lane = gid & 63;
  int nt   = (gid >> 6) & 7;
  int kt   = (gid >> 9) & 3;
  int mat  = gid >> 11;
  const float* w;
  if (mat < 6)       w = Wl_t + (size_t)mat * MSZ;
  else if (mat < 12) w = Wr_t + (size_t)(mat - 6) * MSZ;
  else if (mat < 16) w = Wl_s + (size_t)(mat - 12) * MSZ;
  else               w = Wr_s + (size_t)(mat - 16) * MSZ;
  half_t* o = out + (size_t)mat * MSZ + (size_t)(((kt * 8 + nt) * 64 + lane)) * 8;
  int kbase = kt * 32 + (lane >> 4) * 8;
  int n = nt * 16 + (lane & 15);
  #pragma unroll
  for (int i = 0; i < 8; ++i) o[i] = (_Float16)w[(size_t)(kbase + i) * HDIM + n];
}

// ---------------- gather: packed-f16 mean-aggregate, 4-wide edge batching ----

__device__ __forceinline__ void gather_mean_pk(const half_t* __restrict__ xsrc,
                                               const int* __restrict__ rowptr,
                                               const int* __restrict__ colidx,
                                               int node, int f0, f16x8& s0, f16x8& s1) {
  s0 = f16x8_zero();
  s1 = f16x8_zero();
  int beg = rowptr[node];
  int end = rowptr[node + 1];
  for (int e = beg; e < end; e += 4) {
    int rem = end - e;                    // >= 1
    int i1 = (rem > 1) ? e + 1 : e;
    int i2 = (rem > 2) ? e + 2 : e;
    int i3 = (rem > 3) ? e + 3 : e;
    int c0 = colidx[e], c1 = colidx[i1], c2 = colidx[i2], c3 = colidx[i3];
    const half_t* r0 = &xsrc[(size_t)c0 * HDIM + f0];
    const half_t* r1 = &xsrc[(size_t)c1 * HDIM + f0];
    const half_t* r2 = &xsrc[(size_t)c2 * HDIM + f0];
    const half_t* r3 = &xsrc[(size_t)c3 * HDIM + f0];
    f16x8 p0 = *(const f16x8*)r0,       p1 = *(const f16x8*)(r0 + 8);
    f16x8 q0 = *(const f16x8*)r1,       q1 = *(const f16x8*)(r1 + 8);
    f16x8 t0 = *(const f16x8*)r2,       t1 = *(const f16x8*)(r2 + 8);
    f16x8 u0 = *(const f16x8*)r3,       u1 = *(const f16x8*)(r3 + 8);
    if (rem < 2) { q0 = f16x8_zero(); q1 = f16x8_zero(); }
    if (rem < 3) { t0 = f16x8_zero(); t1 = f16x8_zero(); }
    if (rem < 4) { u0 = f16x8_zero(); u1 = f16x8_zero(); }
    s0 = s0 + ((p0 + q0) + (t0 + u0));
    s1 = s1 + ((p1 + q1) + (t1 + u1));
  }
  int dg = end - beg;
  if (dg > 1) {
    _Float16 hinv = (_Float16)(1.0f / (float)dg);
    #pragma unroll
    for (int j = 0; j < 8; ++j) { s0[j] *= hinv; s1[j] *= hinv; }
  }
}

// swizzled LDS tile store: [node][feat] f16, byte ^= (ni&7)<<4
__device__ __forceinline__ void st_tile_h(half_t* __restrict__ tile, int ni, int c,
                                          f16x8 lo, f16x8 hi) {
  unsigned sw = (unsigned)(ni & 7) << 4;
  unsigned b0 = (unsigned)(ni * 256 + c * 32);
  *(f16x8*)((char*)tile + ((b0     ) ^ sw)) = lo;
  *(f16x8*)((char*)tile + ((b0 + 16) ^ sw)) = hi;
}

// x-direct fragment load: row fragments straight from global (x tile is L1/L2-hot,
// shared by all 4 waves) — removes the lds_x staging tile entirely.
__device__ __forceinline__ void ld_xfrag(const half_t* __restrict__ xdst, int rowc,
                                         int lg, f16x8 (&axx)[4]) {
  const half_t* xp = xdst + (size_t)rowc * HDIM + lg * 8;
  #pragma unroll
  for (int kt = 0; kt < 4; ++kt)
    axx[kt] = *(const f16x8*)(xp + kt * 32);
}

// ---------------- simple SAGE block: out = lrelu(normalize(agg@Wl+bl+x@Wr)) ----

__device__ __forceinline__ void sage_simple_block(
    int n0, int n_dst,
    const half_t* __restrict__ xsrc, const half_t* __restrict__ xdst,
    const int* __restrict__ rowptr, const int* __restrict__ colidx,
    const half_t* __restrict__ pWl, const float* __restrict__ bl,
    const half_t* __restrict__ pWr,
    half_t* __restrict__ out_h, float* __restrict__ out_f, int wf32,
    half_t* __restrict__ lds_a, float (*lds_nrm)[4],
    int tid)
{
  // phase 1: gather only (x fragments come straight from global in phase 2)
  {
    int ni = tid >> 3, c = tid & 7, f0 = c * 16;
    int node = n0 + ni;
    f16x8 s0 = f16x8_zero(), s1 = f16x8_zero();
    if (node < n_dst) {
      gather_mean_pk(xsrc, rowptr, colidx, node, f0, s0, s1);
    }
    st_tile_h(lds_a, ni, c, s0, s1);
  }
  __syncthreads();

  // phase 2
  int lane = tid & 63, wid = tid >> 6;
  int m0 = (wid & 1) * 16;
  int colbase = (wid >> 1) * 64;
  int lg = lane >> 4, ln = lane & 15;

  int row = m0 + ln;
  int rowc = n0 + row; if (rowc > n_dst - 1) rowc = n_dst - 1;
  f16x8 aag[4], axx[4];
  {
    unsigned rsw = (unsigned)(row & 7) << 4;
    #pragma unroll
    for (int kt = 0; kt < 4; ++kt) {
      unsigned byt = ((unsigned)(row * 256 + kt * 64 + lg * 16)) ^ rsw;
      aag[kt] = *(const f16x8*)((const char*)lds_a + byt);
    }
    ld_xfrag(xdst, rowc, lg, axx);
  }

  f32x4 acc[4];
  #pragma unroll
  for (int t = 0; t < 4; ++t) {
    float blv = bl[colbase + t * 16 + ln];
    acc[t] = (f32x4){blv, blv, blv, blv};
  }

  #pragma unroll
  for (int t = 0; t < 4; ++t) {
    int ntg = (colbase >> 4) + t;
    #pragma unroll
    for (int kt = 0; kt < 4; ++kt) {
      size_t boff = (size_t)(((kt * 8 + ntg) * 64 + lane)) * 8;
      f16x8 bwl = *(const f16x8*)(pWl + boff);
      f16x8 bwr = *(const f16x8*)(pWr + boff);
      acc[t] = __builtin_amdgcn_mfma_f32_16x16x32_f16(aag[kt], bwl, acc[t], 0, 0, 0);
      acc[t] = __builtin_amdgcn_mfma_f32_16x16x32_f16(axx[kt], bwr, acc[t], 0, 0, 0);
    }
  }

  // phase 3
  float ss[4];
  #pragma unroll
  for (int r = 0; r < 4; ++r) {
    ss[r] = acc[0][r]*acc[0][r] + acc[1][r]*acc[1][r] + acc[2][r]*acc[2][r] + acc[3][r]*acc[3][r];
    ss[r] += __shfl_xor(ss[r], 1);
    ss[r] += __shfl_xor(ss[r], 2);
    ss[r] += __shfl_xor(ss[r], 4);
    ss[r] += __shfl_xor(ss[r], 8);
  }
  if (ln == 0) {
    #pragma unroll
    for (int r = 0; r < 4; ++r) lds_nrm[m0 + lg * 4 + r][wid >> 1] = ss[r];
  }
  __syncthreads();

  #pragma unroll
  for (int r = 0; r < 4; ++r) {
    int m = m0 + lg * 4 + r;
    int node = n0 + m;
    float tot = lds_nrm[m][0] + lds_nrm[m][1];
    float inv = 1.0f / fmaxf(sqrtf(tot), 1e-12f);
    if (node < n_dst) {
      #pragma unroll
      for (int t = 0; t < 4; ++t) {
        int col = colbase + t * 16 + ln;
        float v = acc[t][r] * inv;
        v = (v >= 0.f) ? v : 0.01f * v;
        if (wf32) out_f[(size_t)node * HDIM + col] = v;
        else      out_h[(size_t)node * HDIM + col] = (_Float16)v;
      }
    }
  }
}

// ---------------- temporal combo: fused con (csrc+cdst, 2 a-tiles) + ipip ----------------
// launch_bounds (256,7): VGPR cap 73 >= used (~56); (256,8)'s cap 64 spilled in R12
// (WRITE_SIZE 62.5->156MB). x fragments are global-direct so LDS = 2 tiles = 16.9KB.

__global__ __launch_bounds__(256, 7) void temporal_kernel(
    const half_t* __restrict__ x_ip, const half_t* __restrict__ x_con,
    const int* __restrict__ rp_ipip, const int* __restrict__ rp_csrc, const int* __restrict__ rp_cdst,
    const int* __restrict__ col_all,
    const half_t* __restrict__ pWl_ip, const float* __restrict__ bl_ip, const half_t* __restrict__ pWr_ip,
    const half_t* __restrict__ pWl_c1, const float* __restrict__ bl_c1, const half_t* __restrict__ pWr_c1,
    const half_t* __restrict__ pWl_c2, const float* __restrict__ bl_c2, const half_t* __restrict__ pWr_c2,
    half_t* __restrict__ Y_ip, half_t* __restrict__ Y_con,
    int n_ip, int n_con, int nb_con)
{
  __shared__ half_t lds[2 * NT * HDIM] __attribute__((aligned(16)));
  __shared__ float lds_nrm[NT][4];
  int tid = threadIdx.x;

  if ((int)blockIdx.x >= nb_con) {
    int n0 = ((int)blockIdx.x - nb_con) * NT;
    sage_simple_block(n0, n_ip, x_ip, x_ip, rp_ipip, col_all,
                      pWl_ip, bl_ip, pWr_ip, Y_ip, nullptr, 0,
                      lds, lds_nrm, tid);
    return;
  }

  int n0 = (int)blockIdx.x * NT;
  half_t* lds_a1 = lds;
  half_t* lds_a2 = lds + NT * HDIM;

  {
    int ni = tid >> 3, ch = tid & 7, f0 = ch * 16;
    int node = n0 + ni;
    f16x8 s0 = f16x8_zero(), s1 = f16x8_zero();
    if (node < n_con) gather_mean_pk(x_con, rp_csrc, col_all, node, f0, s0, s1);
    st_tile_h(lds_a1, ni, ch, s0, s1);
    s0 = f16x8_zero(); s1 = f16x8_zero();
    if (node < n_con) gather_mean_pk(x_con, rp_cdst, col_all, node, f0, s0, s1);
    st_tile_h(lds_a2, ni, ch, s0, s1);
  }
  __syncthreads();

  int lane = tid & 63, wid = tid >> 6;
  int m0 = (wid & 1) * 16;
  int colbase = (wid >> 1) * 64;
  int lg = lane >> 4, ln = lane & 15;
  int row = m0 + ln;
  int rowc = n0 + row; if (rowc > n_con - 1) rowc = n_con - 1;
  unsigned rsw = (unsigned)(row & 7) << 4;
  unsigned byt[4];
  #pragma unroll
  for (int kt = 0; kt < 4; ++kt)
    byt[kt] = ((unsigned)(row * 256 + kt * 64 + lg * 16)) ^ rsw;

  f16x8 axx[4], afr[4];
  ld_xfrag(x_con, rowc, lg, axx);

  f32x4 acc1[4], acc2[4];
  #pragma unroll
  for (int t = 0; t < 4; ++t) {
    float b1 = bl_c1[colbase + t * 16 + ln];
    float b2 = bl_c2[colbase + t * 16 + ln];
    acc1[t] = (f32x4){b1, b1, b1, b1};
    acc2[t] = (f32x4){b2, b2, b2, b2};
  }

  #pragma unroll
  for (int kt = 0; kt < 4; ++kt) afr[kt] = *(const f16x8*)((const char*)lds_a1 + byt[kt]);
  #pragma unroll
  for (int t = 0; t < 4; ++t) {
    int ntg = (colbase >> 4) + t;
    #pragma unroll
    for (int kt = 0; kt < 4; ++kt) {
      size_t boff = (size_t)(((kt * 8 + ntg) * 64 + lane)) * 8;
      f16x8 bwl = *(const f16x8*)(pWl_c1 + boff);
      f16x8 bwr = *(const f16x8*)(pWr_c1 + boff);
      acc1[t] = __builtin_amdgcn_mfma_f32_16x16x32_f16(afr[kt], bwl, acc1[t], 0, 0, 0);
      acc1[t] = __builtin_amdgcn_mfma_f32_16x16x32_f16(axx[kt], bwr, acc1[t], 0, 0, 0);
    }
  }
  #pragma unroll
  for (int kt = 0; kt < 4; ++kt) afr[kt] = *(const f16x8*)((const char*)lds_a2 + byt[kt]);
  #pragma unroll
  for (int t = 0; t < 4; ++t) {
    int ntg = (colbase >> 4) + t;
    #pragma unroll
    for (int kt = 0; kt < 4; ++kt) {
      size_t boff = (size_t)(((kt * 8 + ntg) * 64 + lane)) * 8;
      f16x8 bwl = *(const f16x8*)(pWl_c2 + boff);
      f16x8 bwr = *(const f16x8*)(pWr_c2 + boff);
      acc2[t] = __builtin_amdgcn_mfma_f32_16x16x32_f16(afr[kt], bwl, acc2[t], 0, 0, 0);
      acc2[t] = __builtin_amdgcn_mfma_f32_16x16x32_f16(axx[kt], bwr, acc2[t], 0, 0, 0);
    }
  }

  float ss1[4], ss2[4];
  #pragma unroll
  for (int r = 0; r < 4; ++r) {
    ss1[r] = acc1[0][r]*acc1[0][r] + acc1[1][r]*acc1[1][r] + acc1[2][r]*acc1[2][r] + acc1[3][r]*acc1[3][r];
    ss2[r] = acc2[0][r]*acc2[0][r] + acc2[1][r]*acc2[1][r] + acc2[2][r]*acc2[2][r] + acc2[3][r]*acc2[3][r];
    #pragma unroll
    for (int o = 1; o < 16; o <<= 1) {
      ss1[r] += __shfl_xor(ss1[r], o);
      ss2[r] += __shfl_xor(ss2[r], o);
    }
  }
  if (ln == 0) {
    #pragma unroll
    for (int r = 0; r < 4; ++r) {
      lds_nrm[m0 + lg * 4 + r][(wid >> 1)]     = ss1[r];
      lds_nrm[m0 + lg * 4 + r][2 + (wid >> 1)] = ss2[r];
    }
  }
  __syncthreads();

  #pragma unroll
  for (int r = 0; r < 4; ++r) {
    int m = m0 + lg * 4 + r;
    int node = n0 + m;
    float inv1 = 1.0f / fmaxf(sqrtf(lds_nrm[m][0] + lds_nrm[m][1]), 1e-12f);
    float inv2 = 1.0f / fmaxf(sqrtf(lds_nrm[m][2] + lds_nrm[m][3]), 1e-12f);
    if (node < n_con) {
      #pragma unroll
      for (int t = 0; t < 4; ++t) {
        int col = colbase + t * 16 + ln;
        float v = acc1[t][r] * inv1 + acc2[t][r] * inv2;
        v = (v >= 0.f) ? v : 0.01f * v;
        Y_con[(size_t)node * HDIM + col] = (_Float16)v;
      }
    }
  }
}

// ---------------- spatial combo: ipcon + conip ----------------

__global__ __launch_bounds__(256, 8) void spatial_kernel(
    const half_t* __restrict__ Y_ip, const half_t* __restrict__ Y_con,
    const int* __restrict__ rp_ipcon, const int* __restrict__ rp_conip,
    const int* __restrict__ col_all,
    const half_t* __restrict__ pWl_ic, const float* __restrict__ bl_ic, const half_t* __restrict__ pWr_ic,
    const half_t* __restrict__ pWl_ci, const float* __restrict__ bl_ci, const half_t* __restrict__ pWr_ci,
    half_t* __restrict__ zh_ip, half_t* __restrict__ zh_con,
    float* __restrict__ out_ip, float* __restrict__ out_con,
    int wf32, int n_ip, int n_con, int nb_con)
{
  __shared__ half_t lds[NT * HDIM] __attribute__((aligned(16)));
  __shared__ float lds_nrm[NT][4];
  int tid = threadIdx.x;

  if ((int)blockIdx.x < nb_con) {
    int n0 = (int)blockIdx.x * NT;
    sage_simple_block(n0, n_con, Y_ip, Y_con, rp_ipcon, col_all,
                      pWl_ic, bl_ic, pWr_ic, zh_con, out_con, wf32,
                      lds, lds_nrm, tid);
  } else {
    int n0 = ((int)blockIdx.x - nb_con) * NT;
    sage_simple_block(n0, n_ip, Y_con, Y_ip, rp_conip, col_all,
                      pWl_ci, bl_ci, pWr_ci, zh_ip, out_ip, wf32,
                      lds, lds_nrm, tid);
  }
}

// ---------------- host launch ----------------

extern "C" void kernel_launch(void* const* d_in, const int* in_sizes, int n_in,
                              void* d_out, int out_size, void* d_ws, size_t ws_size,
                              hipStream_t stream) {
  (void)n_in; (void)out_size; (void)ws_size;
  const float* x_ip  = (const float*)d_in[0];
  const float* x_con = (const float*)d_in[1];
  const int* src_ipcon = (const int*)d_in[2];
  const int* dst_ipcon = (const int*)d_in[3];
  const int* src_conip = (const int*)d_in[4];
  const int* dst_conip = (const int*)d_in[5];
  const int* src_ipip  = (const int*)d_in[6];
  const int* dst_ipip  = (const int*)d_in[7];
  const int* src_csrc  = (const int*)d_in[8];
  const int* dst_csrc  = (const int*)d_in[9];
  const int* src_cdst  = (const int*)d_in[10];
  const int* dst_cdst  = (const int*)d_in[11];
  const float* Wl_t = (const float*)d_in[12];
  const float* bl_t = (const float*)d_in[13];
  const float* Wr_t = (const float*)d_in[14];
  const float* Wl_s = (const float*)d_in[15];
  const float* bl_s = (const float*)d_in[16];
  const float* Wr_s = (const float*)d_in[17];

  const int n_ip  = in_sizes[0] / HDIM;
  const int n_con = in_sizes[1] / HDIM;
  const int E_ipcon = in_sizes[2];
  const int E_conip = in_sizes[4];
  const int E_ipip  = in_sizes[6];
  const int E_csrc  = in_sizes[8];
  const int E_cdst  = in_sizes[10];

  const int no_ipip  = 0;
  const int no_csrc  = n_ip;
  const int no_cdst  = n_ip + n_con;
  const int no_ipcon = n_ip + 2 * n_con;
  const int no_conip = n_ip + 3 * n_con;
  const int Ntot = 2 * n_ip + 3 * n_con;
  const int eb1 = E_ipip;
  const int eb2 = eb1 + E_csrc;
  const int eb3 = eb2 + E_cdst;
  const int eb4 = eb3 + E_ipcon;
  const int Etot = eb4 + E_conip;
  const int NB = (Ntot + (1 << BSH) - 1) >> BSH;
  const int chunk = (Etot + NBLK - 1) / NBLK;

  char* ws = (char*)d_ws;
  size_t off = 0;
  auto alloc = [&](size_t bytes) -> void* {
    off = (off + 255) & ~(size_t)255;
    void* p = ws + off;
    off += bytes;
    return p;
  };
  half_t* xh_ip  = (half_t*)alloc((size_t)n_ip * HDIM * 2);
  half_t* xh_con = (half_t*)alloc((size_t)n_con * HDIM * 2);
  half_t* Yh_ip  = (half_t*)alloc((size_t)n_ip * HDIM * 2);
  half_t* Yh_con = (half_t*)alloc((size_t)n_con * HDIM * 2);
  int* cur_all = (int*)alloc((size_t)Ntot * 4);
  int* rp_all  = (int*)alloc((size_t)(Ntot + 1) * 4);
  int* col_all = (int*)alloc((size_t)Etot * 4);
  int* partials = (int*)alloc(256 * 4);
  int* counts  = (int*)alloc((size_t)NBLK * NB * 4);
  int* offs    = (int*)alloc((size_t)NBLK * NB * 4);
  int* totals  = (int*)alloc((size_t)MAXNB * 4);
  int* ebuf_d  = (int*)alloc((size_t)Etot * 4);
  int* ebuf_s  = (int*)alloc((size_t)Etot * 4);
  half_t* pW = (half_t*)alloc((size_t)20 * MSZ * 2);

  (void)hipMemsetAsync(cur_all, 0, (size_t)Ntot * 4, stream);

  BuildArgs ba;
  ba.src0 = src_ipip;  ba.dst0 = dst_ipip;
  ba.src1 = src_csrc;  ba.dst1 = dst_csrc;
  ba.src2 = src_cdst;  ba.dst2 = dst_cdst;
  ba.src3 = src_ipcon; ba.dst3 = dst_ipcon;
  ba.src4 = src_conip; ba.dst4 = dst_conip;
  ba.eb1 = eb1; ba.eb2 = eb2; ba.eb3 = eb3; ba.eb4 = eb4; ba.eb5 = Etot;
  ba.no0 = no_ipip; ba.no1 = no_csrc; ba.no2 = no_cdst; ba.no3 = no_ipcon; ba.no4 = no_conip;

  cvt_f2h_kernel<<<(n_ip * HDIM / 8 + 255) / 256, 256, 0, stream>>>(x_ip, xh_ip, n_ip * HDIM / 8);
  cvt_f2h_kernel<<<(n_con * HDIM / 8 + 255) / 256, 256, 0, stream>>>(x_con, xh_con, n_con * HDIM / 8);
  pack_all_kernel<<<(20 * 2048 + 255) / 256, 256, 0, stream>>>(Wl_t, Wr_t, Wl_s, Wr_s, pW);

  // bucketed CSR build
  bucket_count<<<NBLK, 256, 0, stream>>>(ba, counts, NB, chunk);
  bucket_scan1<<<NB, 256, 0, stream>>>(counts, offs, totals, NB);
  bucket_scan2<<<1, 256, 0, stream>>>(totals, NB);
  bucket_part<<<NBLK, 256, 0, stream>>>(ba, offs, totals, ebuf_d, ebuf_s, NB, chunk);
  hist2_kernel<<<(Etot + 255) / 256, 256, 0, stream>>>(ebuf_d, cur_all, Etot);
  int nb = (Ntot + 4095) / 4096;
  scan_block_sum<<<nb, 256, 0, stream>>>(cur_all, partials, Ntot);
  scan_partials_kernel<<<1, 256, 0, stream>>>(partials, rp_all, nb, Ntot);
  scan_within<<<nb, 256, 0, stream>>>(cur_all, partials, rp_all, Ntot);
  scatter2_kernel<<<(Etot + 255) / 256, 256, 0, stream>>>(ebuf_d, ebuf_s, cur_all, col_all, Etot);

  float* out_ip  = (float*)d_out;
  float* out_con = (float*)d_out + (size_t)n_ip * HDIM;

  const int nb_con = (n_con + NT - 1) / NT;
  const int nb_ip  = (n_ip + NT - 1) / NT;

  const half_t* cip  = xh_ip;
  const half_t* ccon = xh_con;
  for (int l = 0; l < 2; ++l) {
    const half_t* pWl_ip = pW + (size_t)(l * 3 + 0) * MSZ;
    const half_t* pWr_ip = pW + (size_t)(6 + l * 3 + 0) * MSZ;
    const half_t* pWl_c1 = pW + (size_t)(l * 3 + 1) * MSZ;
    const half_t* pWr_c1 = pW + (size_t)(6 + l * 3 + 1) * MSZ;
    const half_t* pWl_c2 = pW + (size_t)(l * 3 + 2) * MSZ;
    const half_t* pWr_c2 = pW + (size_t)(6 + l * 3 + 2) * MSZ;
    temporal_kernel<<<nb_con + nb_ip, 256, 0, stream>>>(
        cip, ccon,
        rp_all + no_ipip, rp_all + no_csrc, rp_all + no_cdst, col_all,
        pWl_ip, bl_t + (l * 3 + 0) * HDIM, pWr_ip,
        pWl_c1, bl_t + (l * 3 + 1) * HDIM, pWr_c1,
        pWl_c2, bl_t + (l * 3 + 2) * HDIM, pWr_c2,
        Yh_ip, Yh_con, n_ip, n_con, nb_con);

    const half_t* pWl_ic = pW + (size_t)(12 + l * 2 + 0) * MSZ;
    const half_t* pWr_ic = pW + (size_t)(16 + l * 2 + 0) * MSZ;
    const half_t* pWl_ci = pW + (size_t)(12 + l * 2 + 1) * MSZ;
    const half_t* pWr_ci = pW + (size_t)(16 + l * 2 + 1) * MSZ;
    spatial_kernel<<<nb_con + nb_ip, 256, 0, stream>>>(
        Yh_ip, Yh_con,
        rp_all + no_ipcon, rp_all + no_conip, col_all,
        pWl_ic, bl_s + (l * 2 + 0) * HDIM, pWr_ic,
        pWl_ci, bl_s + (l * 2 + 1) * HDIM, pWr_ci,
        xh_ip, xh_con, out_ip, out_con, (l == 1) ? 1 : 0,
        n_ip, n_con, nb_con);

    cip = xh_ip;
    ccon = xh_con;
  }
}

// Round 17
// 611.076 us; speedup vs baseline: 1.0463x; 1.0463x over previous
//
#include <hip/hip_runtime.h>

#define HDIM 128
#define NT 32
#define MSZ (HDIM * HDIM)
#define NBLK 512        // blocks for bucket passes
#define MAXNB 1024      // max buckets (Ntot < 1M nodes)
#define BSH 10          // bucket = global_node >> BSH

typedef _Float16 half_t;
typedef __attribute__((ext_vector_type(8))) _Float16 f16x8;
typedef __attribute__((ext_vector_type(4))) float f32x4;

__device__ __forceinline__ f16x8 f16x8_zero() {
  f16x8 v = {0, 0, 0, 0, 0, 0, 0, 0};
  return v;
}

// ---------------- combined edge domain ----------------
// Node domain: [ipip(n_ip) | csrc(n_con) | cdst(n_con) | ipcon(n_con) | conip(n_ip)]

struct BuildArgs {
  const int* src0; const int* dst0;
  const int* src1; const int* dst1;
  const int* src2; const int* dst2;
  const int* src3; const int* dst3;
  const int* src4; const int* dst4;
  int eb1, eb2, eb3, eb4, eb5;
  int no0, no1, no2, no3, no4;
};

__device__ __forceinline__ void resolve(const BuildArgs& a, int gid,
                                        const int*& sp, const int*& dp, int& base, int& no) {
  sp = a.src0; dp = a.dst0; base = 0; no = a.no0;
  if (gid >= a.eb1) { sp = a.src1; dp = a.dst1; base = a.eb1; no = a.no1; }
  if (gid >= a.eb2) { sp = a.src2; dp = a.dst2; base = a.eb2; no = a.no2; }
  if (gid >= a.eb3) { sp = a.src3; dp = a.dst3; base = a.eb3; no = a.no3; }
  if (gid >= a.eb4) { sp = a.src4; dp = a.dst4; base = a.eb4; no = a.no4; }
}

// ---- pass A: per-block bucket histogram ----
__global__ void bucket_count(BuildArgs a, int* __restrict__ counts, int NB, int chunk) {
  __shared__ int h[MAXNB];
  for (int i = threadIdx.x; i < NB; i += 256) h[i] = 0;
  __syncthreads();
  int b = blockIdx.x;
  int lo = b * chunk;
  int hi = lo + chunk; if (hi > a.eb5) hi = a.eb5;
  for (int e = lo + threadIdx.x; e < hi; e += 256) {
    const int *sp, *dp; int base, no;
    resolve(a, e, sp, dp, base, no);
    int g = no + dp[e - base];
    atomicAdd(&h[g >> BSH], 1);
  }
  __syncthreads();
  for (int i = threadIdx.x; i < NB; i += 256) counts[b * NB + i] = h[i];
}

// ---- pass S1: per-bucket exclusive scan over the 512 block counts ----
__global__ void bucket_scan1(const int* __restrict__ counts, int* __restrict__ offs,
                             int* __restrict__ totals, int NB) {
  __shared__ int wsum[4];
  int j = blockIdx.x;
  int t = threadIdx.x;
  int v0 = counts[(2 * t) * NB + j];
  int v1 = counts[(2 * t + 1) * NB + j];
  int s = v0 + v1;
  int lane = t & 63, w = t >> 6;
  int v = s;
  #pragma unroll
  for (int o = 1; o < 64; o <<= 1) {
    int u = __shfl_up(v, o);
    if (lane >= o) v += u;
  }
  if (lane == 63) wsum[w] = v;
  __syncthreads();
  int off = v - s;
  for (int i = 0; i < w; ++i) off += wsum[i];
  offs[(2 * t) * NB + j] = off;
  offs[(2 * t + 1) * NB + j] = off + v0;
  if (t == 255) totals[j] = off + s;
}

// ---- pass S2: exclusive scan over bucket totals -> bases (in place) ----
__global__ void bucket_scan2(int* __restrict__ totals, int NB) {
  __shared__ int buf[MAXNB];
  __shared__ int wsum[4];
  int t = threadIdx.x;
  for (int i = t; i < MAXNB; i += 256) buf[i] = (i < NB) ? totals[i] : 0;
  __syncthreads();
  int e0 = buf[4 * t], e1 = buf[4 * t + 1], e2 = buf[4 * t + 2], e3 = buf[4 * t + 3];
  int s = e0 + e1 + e2 + e3;
  int lane = t & 63, w = t >> 6;
  int v = s;
  #pragma unroll
  for (int o = 1; o < 64; o <<= 1) {
    int u = __shfl_up(v, o);
    if (lane >= o) v += u;
  }
  if (lane == 63) wsum[w] = v;
  __syncthreads();
  int off = v - s;
  for (int i = 0; i < w; ++i) off += wsum[i];
  if (4 * t     < NB) totals[4 * t]     = off;
  if (4 * t + 1 < NB) totals[4 * t + 1] = off + e0;
  if (4 * t + 2 < NB) totals[4 * t + 2] = off + e0 + e1;
  if (4 * t + 3 < NB) totals[4 * t + 3] = off + e0 + e1 + e2;
}

// ---- pass B: partition edges into bucket-grouped (dst,src) arrays ----
__global__ void bucket_part(BuildArgs a, const int* __restrict__ offs,
                            const int* __restrict__ bases,
                            int* __restrict__ ebuf_d, int* __restrict__ ebuf_s,
                            int NB, int chunk) {
  __shared__ int cur[MAXNB];
  int b = blockIdx.x;
  for (int i = threadIdx.x; i < NB; i += 256) cur[i] = bases[i] + offs[b * NB + i];
  __syncthreads();
  int lo = b * chunk;
  int hi = lo + chunk; if (hi > a.eb5) hi = a.eb5;
  for (int e = lo + threadIdx.x; e < hi; e += 256) {
    const int *sp, *dp; int base, no;
    resolve(a, e, sp, dp, base, no);
    int g = no + dp[e - base];
    int p = atomicAdd(&cur[g >> BSH], 1);
    ebuf_d[p] = g;
    ebuf_s[p] = sp[e - base];
  }
}

// ---- hist / scatter on bucketed edges (L2-local addresses) ----
__global__ void hist2_kernel(const int* __restrict__ ebuf_d, int* __restrict__ deg, int E) {
  int e = blockIdx.x * 256 + threadIdx.x;
  if (e < E) atomicAdd(&deg[ebuf_d[e]], 1);
}

__global__ void scatter2_kernel(const int* __restrict__ ebuf_d, const int* __restrict__ ebuf_s,
                                int* __restrict__ cursor, int* __restrict__ col, int E) {
  int e = blockIdx.x * 256 + threadIdx.x;
  if (e < E) {
    int p = atomicAdd(&cursor[ebuf_d[e]], 1);
    col[p] = ebuf_s[e];
  }
}

// ---- rowptr scans ----
__global__ void scan_block_sum(const int* __restrict__ deg, int* __restrict__ partials, int n) {
  __shared__ int red[256];
  int t = threadIdx.x;
  int base = blockIdx.x * 4096;
  int s = 0;
  #pragma unroll
  for (int i = 0; i < 16; ++i) {
    int idx = base + t + i * 256;
    if (idx < n) s += deg[idx];
  }
  red[t] = s;
  __syncthreads();
  for (int o = 128; o > 0; o >>= 1) {
    if (t < o) red[t] += red[t + o];
    __syncthreads();
  }
  if (t == 0) partials[blockIdx.x] = red[0];
}

// parallel exclusive scan over <=256 block partials
__global__ void scan_partials_kernel(int* __restrict__ partials, int* __restrict__ rowptr,
                                     int nb, int n) {
  __shared__ int wsum[4];
  int t = threadIdx.x;
  int v0 = (t < nb) ? partials[t] : 0;
  int lane = t & 63, w = t >> 6;
  int v = v0;
  #pragma unroll
  for (int o = 1; o < 64; o <<= 1) {
    int u = __shfl_up(v, o);
    if (lane >= o) v += u;
  }
  if (lane == 63) wsum[w] = v;
  __syncthreads();
  int off = v - v0;
  for (int i = 0; i < w; ++i) off += wsum[i];
  if (t < nb) partials[t] = off;
  if (t == 255) rowptr[n] = off + v0;
}

__global__ void scan_within(int* __restrict__ deg_cursor, const int* __restrict__ partials,
                            int* __restrict__ rowptr, int n) {
  __shared__ int buf[4096];
  __shared__ int wsum[4];
  int t = threadIdx.x;
  int base = blockIdx.x * 4096;
  #pragma unroll
  for (int i = 0; i < 16; ++i) {
    int idx = base + t + i * 256;
    buf[t + i * 256] = (idx < n) ? deg_cursor[idx] : 0;
  }
  __syncthreads();
  int ex[16];
  int s = 0;
  #pragma unroll
  for (int i = 0; i < 16; ++i) { ex[i] = s; s += buf[t * 16 + i]; }
  int lane = t & 63, w = t >> 6;
  int v = s;
  #pragma unroll
  for (int o = 1; o < 64; o <<= 1) {
    int u = __shfl_up(v, o);
    if (lane >= o) v += u;
  }
  if (lane == 63) wsum[w] = v;
  __syncthreads();
  int off = partials[blockIdx.x] + (v - s);
  for (int i = 0; i < w; ++i) off += wsum[i];
  #pragma unroll
  for (int i = 0; i < 16; ++i) {
    int idx = base + t * 16 + i;
    if (idx < n) { int val = off + ex[i]; rowptr[idx] = val; deg_cursor[idx] = val; }
  }
}

// ---------------- fp32 -> f16 input conversion ----------------

__global__ void cvt_f2h_kernel(const float* __restrict__ in, half_t* __restrict__ out, int n8) {
  int i = blockIdx.x * 256 + threadIdx.x;
  if (i >= n8) return;
  const float4* p = (const float4*)(in + (size_t)i * 8);
  float4 a = p[0], b = p[1];
  f16x8 h = { (_Float16)a.x, (_Float16)a.y, (_Float16)a.z, (_Float16)a.w,
              (_Float16)b.x, (_Float16)b.y, (_Float16)b.z, (_Float16)b.w };
  *(f16x8*)(out + (size_t)i * 8) = h;
}

// ---------------- weight pack: fp32 row-major -> f16 MFMA B-fragment order ----

__global__ void pack_all_kernel(const float* __restrict__ Wl_t, const float* __restrict__ Wr_t,
                                const float* __restrict__ Wl_s, const float* __restrict__ Wr_s,
                                half_t* __restrict__ out) {
  int gid = blockIdx.x * 256 + threadIdx.x;
  if (gid >= 20 * 2048) return;
  int lane = gid & 63;
  int nt   = (gid >> 6) & 7;
  int kt   = (gid >> 9) & 3;
  int mat  = gid >> 11;
  const float* w;
  if (mat < 6)       w = Wl_t + (size_t)mat * MSZ;
  else if (mat < 12) w = Wr_t + (size_t)(mat - 6) * MSZ;
  else if (mat < 16) w = Wl_s + (size_t)(mat - 12) * MSZ;
  else               w = Wr_s + (size_t)(mat - 16) * MSZ;
  half_t* o = out + (size_t)mat * MSZ + (size_t)(((kt * 8 + nt) * 64 + lane)) * 8;
  int kbase = kt * 32 + (lane >> 4) * 8;
  int n = nt * 16 + (lane & 15);
  #pragma unroll
  for (int i = 0; i < 8; ++i) o[i] = (_Float16)w[(size_t)(kbase + i) * HDIM + n];
}

// ---------------- gather: packed-f16 mean-aggregate, 4-wide edge batching ----

__device__ __forceinline__ void gather_mean_pk(const half_t* __restrict__ xsrc,
                                               const int* __restrict__ rowptr,
                                               const int* __restrict__ colidx,
                                               int node, int f0, f16x8& s0, f16x8& s1) {
  s0 = f16x8_zero();
  s1 = f16x8_zero();
  int beg = rowptr[node];
  int end = rowptr[node + 1];
  for (int e = beg; e < end; e += 4) {
    int rem = end - e;                    // >= 1
    int i1 = (rem > 1) ? e + 1 : e;
    int i2 = (rem > 2) ? e + 2 : e;
    int i3 = (rem > 3) ? e + 3 : e;
    int c0 = colidx[e], c1 = colidx[i1], c2 = colidx[i2], c3 = colidx[i3];
    const half_t* r0 = &xsrc[(size_t)c0 * HDIM + f0];
    const half_t* r1 = &xsrc[(size_t)c1 * HDIM + f0];
    const half_t* r2 = &xsrc[(size_t)c2 * HDIM + f0];
    const half_t* r3 = &xsrc[(size_t)c3 * HDIM + f0];
    f16x8 p0 = *(const f16x8*)r0,       p1 = *(const f16x8*)(r0 + 8);
    f16x8 q0 = *(const f16x8*)r1,       q1 = *(const f16x8*)(r1 + 8);
    f16x8 t0 = *(const f16x8*)r2,       t1 = *(const f16x8*)(r2 + 8);
    f16x8 u0 = *(const f16x8*)r3,       u1 = *(const f16x8*)(r3 + 8);
    if (rem < 2) { q0 = f16x8_zero(); q1 = f16x8_zero(); }
    if (rem < 3) { t0 = f16x8_zero(); t1 = f16x8_zero(); }
    if (rem < 4) { u0 = f16x8_zero(); u1 = f16x8_zero(); }
    s0 = s0 + ((p0 + q0) + (t0 + u0));
    s1 = s1 + ((p1 + q1) + (t1 + u1));
  }
  int dg = end - beg;
  if (dg > 1) {
    _Float16 hinv = (_Float16)(1.0f / (float)dg);
    #pragma unroll
    for (int j = 0; j < 8; ++j) { s0[j] *= hinv; s1[j] *= hinv; }
  }
}

// swizzled LDS tile store: [node][feat] f16, byte ^= (ni&7)<<4
__device__ __forceinline__ void st_tile_h(half_t* __restrict__ tile, int ni, int c,
                                          f16x8 lo, f16x8 hi) {
  unsigned sw = (unsigned)(ni & 7) << 4;
  unsigned b0 = (unsigned)(ni * 256 + c * 32);
  *(f16x8*)((char*)tile + ((b0     ) ^ sw)) = lo;
  *(f16x8*)((char*)tile + ((b0 + 16) ^ sw)) = hi;
}

// ---------------- simple SAGE block: out = lrelu(normalize(agg@Wl+bl+x@Wr)) ----

__device__ __forceinline__ void sage_simple_block(
    int n0, int n_dst,
    const half_t* __restrict__ xsrc, const half_t* __restrict__ xdst,
    const int* __restrict__ rowptr, const int* __restrict__ colidx,
    const half_t* __restrict__ pWl, const float* __restrict__ bl,
    const half_t* __restrict__ pWr,
    half_t* __restrict__ out_h, float* __restrict__ out_f, int wf32,
    half_t* __restrict__ lds_a, half_t* __restrict__ lds_x, float (*lds_nrm)[4],
    int tid)
{
  // phase 1
  {
    int ni = tid >> 3, c = tid & 7, f0 = c * 16;
    int node = n0 + ni;
    f16x8 x0 = f16x8_zero(), x1 = f16x8_zero();
    f16x8 s0 = f16x8_zero(), s1 = f16x8_zero();
    if (node < n_dst) {
      const half_t* xd = &xdst[(size_t)node * HDIM + f0];
      x0 = *(const f16x8*)xd;
      x1 = *(const f16x8*)(xd + 8);
      gather_mean_pk(xsrc, rowptr, colidx, node, f0, s0, s1);
    }
    st_tile_h(lds_x, ni, c, x0, x1);
    st_tile_h(lds_a, ni, c, s0, s1);
  }
  __syncthreads();

  // phase 2
  int lane = tid & 63, wid = tid >> 6;
  int m0 = (wid & 1) * 16;
  int colbase = (wid >> 1) * 64;
  int lg = lane >> 4, ln = lane & 15;

  f16x8 aag[4], axx[4];
  {
    int row = m0 + ln;
    unsigned rsw = (unsigned)(row & 7) << 4;
    #pragma unroll
    for (int kt = 0; kt < 4; ++kt) {
      unsigned byt = ((unsigned)(row * 256 + kt * 64 + lg * 16)) ^ rsw;
      aag[kt] = *(const f16x8*)((const char*)lds_a + byt);
      axx[kt] = *(const f16x8*)((const char*)lds_x + byt);
    }
  }

  f32x4 acc[4];
  #pragma unroll
  for (int t = 0; t < 4; ++t) {
    float blv = bl[colbase + t * 16 + ln];
    acc[t] = (f32x4){blv, blv, blv, blv};
  }

  #pragma unroll
  for (int t = 0; t < 4; ++t) {
    int ntg = (colbase >> 4) + t;
    #pragma unroll
    for (int kt = 0; kt < 4; ++kt) {
      size_t boff = (size_t)(((kt * 8 + ntg) * 64 + lane)) * 8;
      f16x8 bwl = *(const f16x8*)(pWl + boff);
      f16x8 bwr = *(const f16x8*)(pWr + boff);
      acc[t] = __builtin_amdgcn_mfma_f32_16x16x32_f16(aag[kt], bwl, acc[t], 0, 0, 0);
      acc[t] = __builtin_amdgcn_mfma_f32_16x16x32_f16(axx[kt], bwr, acc[t], 0, 0, 0);
    }
  }

  // phase 3
  float ss[4];
  #pragma unroll
  for (int r = 0; r < 4; ++r) {
    ss[r] = acc[0][r]*acc[0][r] + acc[1][r]*acc[1][r] + acc[2][r]*acc[2][r] + acc[3][r]*acc[3][r];
    ss[r] += __shfl_xor(ss[r], 1);
    ss[r] += __shfl_xor(ss[r], 2);
    ss[r] += __shfl_xor(ss[r], 4);
    ss[r] += __shfl_xor(ss[r], 8);
  }
  if (ln == 0) {
    #pragma unroll
    for (int r = 0; r < 4; ++r) lds_nrm[m0 + lg * 4 + r][wid >> 1] = ss[r];
  }
  __syncthreads();

  #pragma unroll
  for (int r = 0; r < 4; ++r) {
    int m = m0 + lg * 4 + r;
    int node = n0 + m;
    float tot = lds_nrm[m][0] + lds_nrm[m][1];
    float inv = 1.0f / fmaxf(sqrtf(tot), 1e-12f);
    if (node < n_dst) {
      #pragma unroll
      for (int t = 0; t < 4; ++t) {
        int col = colbase + t * 16 + ln;
        float v = acc[t][r] * inv;
        v = (v >= 0.f) ? v : 0.01f * v;
        if (wf32) out_f[(size_t)node * HDIM + col] = v;
        else      out_h[(size_t)node * HDIM + col] = (_Float16)v;
      }
    }
  }
}

// ---------------- temporal combo: fused con (csrc+cdst, 3-tile LDS) + ipip ----------------
// NOTE: launch_bounds (256,6) — NOT 8 (R12: VGPR cap 64 spilled acc1/acc2, WRITE 62.5->156MB).
// NOTE: keep lds_x staging — x-direct global fragments regressed in R15 (114.5->129us:
// post-barrier L2-latency loads serialized before MFMA; L1 thrash at 7 blocks/CU).

__global__ __launch_bounds__(256, 6) void temporal_kernel(
    const half_t* __restrict__ x_ip, const half_t* __restrict__ x_con,
    const int* __restrict__ rp_ipip, const int* __restrict__ rp_csrc, const int* __restrict__ rp_cdst,
    const int* __restrict__ col_all,
    const half_t* __restrict__ pWl_ip, const float* __restrict__ bl_ip, const half_t* __restrict__ pWr_ip,
    const half_t* __restrict__ pWl_c1, const float* __restrict__ bl_c1, const half_t* __restrict__ pWr_c1,
    const half_t* __restrict__ pWl_c2, const float* __restrict__ bl_c2, const half_t* __restrict__ pWr_c2,
    half_t* __restrict__ Y_ip, half_t* __restrict__ Y_con,
    int n_ip, int n_con, int nb_con)
{
  __shared__ half_t lds[3 * NT * HDIM] __attribute__((aligned(16)));
  __shared__ float lds_nrm[NT][4];
  int tid = threadIdx.x;

  if ((int)blockIdx.x >= nb_con) {
    int n0 = ((int)blockIdx.x - nb_con) * NT;
    sage_simple_block(n0, n_ip, x_ip, x_ip, rp_ipip, col_all,
                      pWl_ip, bl_ip, pWr_ip, Y_ip, nullptr, 0,
                      lds, lds + NT * HDIM, lds_nrm, tid);
    return;
  }

  int n0 = (int)blockIdx.x * NT;
  half_t* lds_x  = lds;
  half_t* lds_a1 = lds + NT * HDIM;
  half_t* lds_a2 = lds + 2 * NT * HDIM;

  {
    int ni = tid >> 3, ch = tid & 7, f0 = ch * 16;
    int node = n0 + ni;
    f16x8 x0 = f16x8_zero(), x1 = f16x8_zero();
    f16x8 s0 = f16x8_zero(), s1 = f16x8_zero();
    if (node < n_con) {
      const half_t* xd = &x_con[(size_t)node * HDIM + f0];
      x0 = *(const f16x8*)xd;
      x1 = *(const f16x8*)(xd + 8);
    }
    st_tile_h(lds_x, ni, ch, x0, x1);
    if (node < n_con) gather_mean_pk(x_con, rp_csrc, col_all, node, f0, s0, s1);
    st_tile_h(lds_a1, ni, ch, s0, s1);
    s0 = f16x8_zero(); s1 = f16x8_zero();
    if (node < n_con) gather_mean_pk(x_con, rp_cdst, col_all, node, f0, s0, s1);
    st_tile_h(lds_a2, ni, ch, s0, s1);
  }
  __syncthreads();

  int lane = tid & 63, wid = tid >> 6;
  int m0 = (wid & 1) * 16;
  int colbase = (wid >> 1) * 64;
  int lg = lane >> 4, ln = lane & 15;
  int row = m0 + ln;
  unsigned rsw = (unsigned)(row & 7) << 4;
  unsigned byt[4];
  #pragma unroll
  for (int kt = 0; kt < 4; ++kt)
    byt[kt] = ((unsigned)(row * 256 + kt * 64 + lg * 16)) ^ rsw;

  f16x8 axx[4], afr[4];
  #pragma unroll
  for (int kt = 0; kt < 4; ++kt) axx[kt] = *(const f16x8*)((const char*)lds_x + byt[kt]);

  f32x4 acc1[4], acc2[4];
  #pragma unroll
  for (int t = 0; t < 4; ++t) {
    float b1 = bl_c1[colbase + t * 16 + ln];
    float b2 = bl_c2[colbase + t * 16 + ln];
    acc1[t] = (f32x4){b1, b1, b1, b1};
    acc2[t] = (f32x4){b2, b2, b2, b2};
  }

  #pragma unroll
  for (int kt = 0; kt < 4; ++kt) afr[kt] = *(const f16x8*)((const char*)lds_a1 + byt[kt]);
  #pragma unroll
  for (int t = 0; t < 4; ++t) {
    int ntg = (colbase >> 4) + t;
    #pragma unroll
    for (int kt = 0; kt < 4; ++kt) {
      size_t boff = (size_t)(((kt * 8 + ntg) * 64 + lane)) * 8;
      f16x8 bwl = *(const f16x8*)(pWl_c1 + boff);
      f16x8 bwr = *(const f16x8*)(pWr_c1 + boff);
      acc1[t] = __builtin_amdgcn_mfma_f32_16x16x32_f16(afr[kt], bwl, acc1[t], 0, 0, 0);
      acc1[t] = __builtin_amdgcn_mfma_f32_16x16x32_f16(axx[kt], bwr, acc1[t], 0, 0, 0);
    }
  }
  #pragma unroll
  for (int kt = 0; kt < 4; ++kt) afr[kt] = *(const f16x8*)((const char*)lds_a2 + byt[kt]);
  #pragma unroll
  for (int t = 0; t < 4; ++t) {
    int ntg = (colbase >> 4) + t;
    #pragma unroll
    for (int kt = 0; kt < 4; ++kt) {
      size_t boff = (size_t)(((kt * 8 + ntg) * 64 + lane)) * 8;
      f16x8 bwl = *(const f16x8*)(pWl_c2 + boff);
      f16x8 bwr = *(const f16x8*)(pWr_c2 + boff);
      acc2[t] = __builtin_amdgcn_mfma_f32_16x16x32_f16(afr[kt], bwl, acc2[t], 0, 0, 0);
      acc2[t] = __builtin_amdgcn_mfma_f32_16x16x32_f16(axx[kt], bwr, acc2[t], 0, 0, 0);
    }
  }

  float ss1[4], ss2[4];
  #pragma unroll
  for (int r = 0; r < 4; ++r) {
    ss1[r] = acc1[0][r]*acc1[0][r] + acc1[1][r]*acc1[1][r] + acc1[2][r]*acc1[2][r] + acc1[3][r]*acc1[3][r];
    ss2[r] = acc2[0][r]*acc2[0][r] + acc2[1][r]*acc2[1][r] + acc2[2][r]*acc2[2][r] + acc2[3][r]*acc2[3][r];
    #pragma unroll
    for (int o = 1; o < 16; o <<= 1) {
      ss1[r] += __shfl_xor(ss1[r], o);
      ss2[r] += __shfl_xor(ss2[r], o);
    }
  }
  if (ln == 0) {
    #pragma unroll
    for (int r = 0; r < 4; ++r) {
      lds_nrm[m0 + lg * 4 + r][(wid >> 1)]     = ss1[r];
      lds_nrm[m0 + lg * 4 + r][2 + (wid >> 1)] = ss2[r];
    }
  }
  __syncthreads();

  #pragma unroll
  for (int r = 0; r < 4; ++r) {
    int m = m0 + lg * 4 + r;
    int node = n0 + m;
    float inv1 = 1.0f / fmaxf(sqrtf(lds_nrm[m][0] + lds_nrm[m][1]), 1e-12f);
    float inv2 = 1.0f / fmaxf(sqrtf(lds_nrm[m][2] + lds_nrm[m][3]), 1e-12f);
    if (node < n_con) {
      #pragma unroll
      for (int t = 0; t < 4; ++t) {
        int col = colbase + t * 16 + ln;
        float v = acc1[t][r] * inv1 + acc2[t][r] * inv2;
        v = (v >= 0.f) ? v : 0.01f * v;
        Y_con[(size_t)node * HDIM + col] = (_Float16)v;
      }
    }
  }
}

// ---------------- spatial combo: ipcon + conip ----------------

__global__ __launch_bounds__(256, 8) void spatial_kernel(
    const half_t* __restrict__ Y_ip, const half_t* __restrict__ Y_con,
    const int* __restrict__ rp_ipcon, const int* __restrict__ rp_conip,
    const int* __restrict__ col_all,
    const half_t* __restrict__ pWl_ic, const float* __restrict__ bl_ic, const half_t* __restrict__ pWr_ic,
    const half_t* __restrict__ pWl_ci, const float* __restrict__ bl_ci, const half_t* __restrict__ pWr_ci,
    half_t* __restrict__ zh_ip, half_t* __restrict__ zh_con,
    float* __restrict__ out_ip, float* __restrict__ out_con,
    int wf32, int n_ip, int n_con, int nb_con)
{
  __shared__ half_t lds[2 * NT * HDIM] __attribute__((aligned(16)));
  __shared__ float lds_nrm[NT][4];
  int tid = threadIdx.x;

  if ((int)blockIdx.x < nb_con) {
    int n0 = (int)blockIdx.x * NT;
    sage_simple_block(n0, n_con, Y_ip, Y_con, rp_ipcon, col_all,
                      pWl_ic, bl_ic, pWr_ic, zh_con, out_con, wf32,
                      lds, lds + NT * HDIM, lds_nrm, tid);
  } else {
    int n0 = ((int)blockIdx.x - nb_con) * NT;
    sage_simple_block(n0, n_ip, Y_con, Y_ip, rp_conip, col_all,
                      pWl_ci, bl_ci, pWr_ci, zh_ip, out_ip, wf32,
                      lds, lds + NT * HDIM, lds_nrm, tid);
  }
}

// ---------------- host launch ----------------

extern "C" void kernel_launch(void* const* d_in, const int* in_sizes, int n_in,
                              void* d_out, int out_size, void* d_ws, size_t ws_size,
                              hipStream_t stream) {
  (void)n_in; (void)out_size; (void)ws_size;
  const float* x_ip  = (const float*)d_in[0];
  const float* x_con = (const float*)d_in[1];
  const int* src_ipcon = (const int*)d_in[2];
  const int* dst_ipcon = (const int*)d_in[3];
  const int* src_conip = (const int*)d_in[4];
  const int* dst_conip = (const int*)d_in[5];
  const int* src_ipip  = (const int*)d_in[6];
  const int* dst_ipip  = (const int*)d_in[7];
  const int* src_csrc  = (const int*)d_in[8];
  const int* dst_csrc  = (const int*)d_in[9];
  const int* src_cdst  = (const int*)d_in[10];
  const int* dst_cdst  = (const int*)d_in[11];
  const float* Wl_t = (const float*)d_in[12];
  const float* bl_t = (const float*)d_in[13];
  const float* Wr_t = (const float*)d_in[14];
  const float* Wl_s = (const float*)d_in[15];
  const float* bl_s = (const float*)d_in[16];
  const float* Wr_s = (const float*)d_in[17];

  const int n_ip  = in_sizes[0] / HDIM;
  const int n_con = in_sizes[1] / HDIM;
  const int E_ipcon = in_sizes[2];
  const int E_conip = in_sizes[4];
  const int E_ipip  = in_sizes[6];
  const int E_csrc  = in_sizes[8];
  const int E_cdst  = in_sizes[10];

  const int no_ipip  = 0;
  const int no_csrc  = n_ip;
  const int no_cdst  = n_ip + n_con;
  const int no_ipcon = n_ip + 2 * n_con;
  const int no_conip = n_ip + 3 * n_con;
  const int Ntot = 2 * n_ip + 3 * n_con;
  const int eb1 = E_ipip;
  const int eb2 = eb1 + E_csrc;
  const int eb3 = eb2 + E_cdst;
  const int eb4 = eb3 + E_ipcon;
  const int Etot = eb4 + E_conip;
  const int NB = (Ntot + (1 << BSH) - 1) >> BSH;
  const int chunk = (Etot + NBLK - 1) / NBLK;

  char* ws = (char*)d_ws;
  size_t off = 0;
  auto alloc = [&](size_t bytes) -> void* {
    off = (off + 255) & ~(size_t)255;
    void* p = ws + off;
    off += bytes;
    return p;
  };
  half_t* xh_ip  = (half_t*)alloc((size_t)n_ip * HDIM * 2);
  half_t* xh_con = (half_t*)alloc((size_t)n_con * HDIM * 2);
  half_t* Yh_ip  = (half_t*)alloc((size_t)n_ip * HDIM * 2);
  half_t* Yh_con = (half_t*)alloc((size_t)n_con * HDIM * 2);
  int* cur_all = (int*)alloc((size_t)Ntot * 4);
  int* rp_all  = (int*)alloc((size_t)(Ntot + 1) * 4);
  int* col_all = (int*)alloc((size_t)Etot * 4);
  int* partials = (int*)alloc(256 * 4);
  int* counts  = (int*)alloc((size_t)NBLK * NB * 4);
  int* offs    = (int*)alloc((size_t)NBLK * NB * 4);
  int* totals  = (int*)alloc((size_t)MAXNB * 4);
  int* ebuf_d  = (int*)alloc((size_t)Etot * 4);
  int* ebuf_s  = (int*)alloc((size_t)Etot * 4);
  half_t* pW = (half_t*)alloc((size_t)20 * MSZ * 2);

  (void)hipMemsetAsync(cur_all, 0, (size_t)Ntot * 4, stream);

  BuildArgs ba;
  ba.src0 = src_ipip;  ba.dst0 = dst_ipip;
  ba.src1 = src_csrc;  ba.dst1 = dst_csrc;
  ba.src2 = src_cdst;  ba.dst2 = dst_cdst;
  ba.src3 = src_ipcon; ba.dst3 = dst_ipcon;
  ba.src4 = src_conip; ba.dst4 = dst_conip;
  ba.eb1 = eb1; ba.eb2 = eb2; ba.eb3 = eb3; ba.eb4 = eb4; ba.eb5 = Etot;
  ba.no0 = no_ipip; ba.no1 = no_csrc; ba.no2 = no_cdst; ba.no3 = no_ipcon; ba.no4 = no_conip;

  cvt_f2h_kernel<<<(n_ip * HDIM / 8 + 255) / 256, 256, 0, stream>>>(x_ip, xh_ip, n_ip * HDIM / 8);
  cvt_f2h_kernel<<<(n_con * HDIM / 8 + 255) / 256, 256, 0, stream>>>(x_con, xh_con, n_con * HDIM / 8);
  pack_all_kernel<<<(20 * 2048 + 255) / 256, 256, 0, stream>>>(Wl_t, Wr_t, Wl_s, Wr_s, pW);

  // bucketed CSR build
  bucket_count<<<NBLK, 256, 0, stream>>>(ba, counts, NB, chunk);
  bucket_scan1<<<NB, 256, 0, stream>>>(counts, offs, totals, NB);
  bucket_scan2<<<1, 256, 0, stream>>>(totals, NB);
  bucket_part<<<NBLK, 256, 0, stream>>>(ba, offs, totals, ebuf_d, ebuf_s, NB, chunk);
  hist2_kernel<<<(Etot + 255) / 256, 256, 0, stream>>>(ebuf_d, cur_all, Etot);
  int nb = (Ntot + 4095) / 4096;
  scan_block_sum<<<nb, 256, 0, stream>>>(cur_all, partials, Ntot);
  scan_partials_kernel<<<1, 256, 0, stream>>>(partials, rp_all, nb, Ntot);
  scan_within<<<nb, 256, 0, stream>>>(cur_all, partials, rp_all, Ntot);
  scatter2_kernel<<<(Etot + 255) / 256, 256, 0, stream>>>(ebuf_d, ebuf_s, cur_all, col_all, Etot);

  float* out_ip  = (float*)d_out;
  float* out_con = (float*)d_out + (size_t)n_ip * HDIM;

  const int nb_con = (n_con + NT - 1) / NT;
  const int nb_ip  = (n_ip + NT - 1) / NT;

  const half_t* cip  = xh_ip;
  const half_t* ccon = xh_con;
  for (int l = 0; l < 2; ++l) {
    const half_t* pWl_ip = pW + (size_t)(l * 3 + 0) * MSZ;
    const half_t* pWr_ip = pW + (size_t)(6 + l * 3 + 0) * MSZ;
    const half_t* pWl_c1 = pW + (size_t)(l * 3 + 1) * MSZ;
    const half_t* pWr_c1 = pW + (size_t)(6 + l * 3 + 1) * MSZ;
    const half_t* pWl_c2 = pW + (size_t)(l * 3 + 2) * MSZ;
    const half_t* pWr_c2 = pW + (size_t)(6 + l * 3 + 2) * MSZ;
    temporal_kernel<<<nb_con + nb_ip, 256, 0, stream>>>(
        cip, ccon,
        rp_all + no_ipip, rp_all + no_csrc, rp_all + no_cdst, col_all,
        pWl_ip, bl_t + (l * 3 + 0) * HDIM, pWr_ip,
        pWl_c1, bl_t + (l * 3 + 1) * HDIM, pWr_c1,
        pWl_c2, bl_t + (l * 3 + 2) * HDIM, pWr_c2,
        Yh_ip, Yh_con, n_ip, n_con, nb_con);

    const half_t* pWl_ic = pW + (size_t)(12 + l * 2 + 0) * MSZ;
    const half_t* pWr_ic = pW + (size_t)(16 + l * 2 + 0) * MSZ;
    const half_t* pWl_ci = pW + (size_t)(12 + l * 2 + 1) * MSZ;
    const half_t* pWr_ci = pW + (size_t)(16 + l * 2 + 1) * MSZ;
    spatial_kernel<<<nb_con + nb_ip, 256, 0, stream>>>(
        Yh_ip, Yh_con,
        rp_all + no_ipcon, rp_all + no_conip, col_all,
        pWl_ic, bl_s + (l * 2 + 0) * HDIM, pWr_ic,
        pWl_ci, bl_s + (l * 2 + 1) * HDIM, pWr_ci,
        xh_ip, xh_con, out_ip, out_con, (l == 1) ? 1 : 0,
        n_ip, n_con, nb_con);

    cip = xh_ip;
    ccon = xh_con;
  }
}